// Round 20
// baseline (548.475 us; speedup 1.0000x reference)
//
#include <hip/hip_runtime.h>
#include <math.h>

#define BB 8
#define NN 4096
#define DDIM 256
#define TT 768
#define BND (BB*NN*DDIM)

typedef unsigned short ushort_t;
typedef short bf16x8 __attribute__((ext_vector_type(8)));
typedef float f32x4 __attribute__((ext_vector_type(4)));

__device__ __forceinline__ float gelu_f(float v){
    float y = 0.7978845608028654f * v * (1.0f + 0.044715f * v * v);
    float ay = fabsf(y);
    float e = __expf(-2.0f * ay);
    float th = 1.0f - 2.0f * e / (1.0f + e);
    th = copysignf(th, y);
    return 0.5f * v * (1.0f + th);
}
__device__ __forceinline__ ushort_t f2bf(float f){
    union { float f; unsigned int u; } v; v.f = f;
    unsigned int u = v.u;
    u += 0x7FFFu + ((u >> 16) & 1u);
    return (ushort_t)(u >> 16);
}
__device__ __forceinline__ float bf2f(ushort_t h){
    union { unsigned int u; float f; } v; v.u = ((unsigned int)h) << 16;
    return v.f;
}
__device__ __forceinline__ float pk_re(unsigned int p){
    union { unsigned int u; float f; } v; v.u = p << 16; return v.f;
}
__device__ __forceinline__ float pk_im(unsigned int p){
    union { unsigned int u; float f; } v; v.u = p & 0xffff0000u; return v.f;
}
__device__ __forceinline__ unsigned int pack_cx(float re, float im){
    return (((unsigned int)f2bf(im)) << 16) | (unsigned int)f2bf(re);
}
#define GLOAD16(gp, lp) __builtin_amdgcn_global_load_lds( \
    (__attribute__((address_space(1))) const void*)(gp),  \
    (__attribute__((address_space(3))) void*)(lp), 16, 0, 0)

// ---------------- fused: LN stats + out=x copy + x_bf + LN1(x)->xln_bf + mean partials ----------------
__global__ __launch_bounds__(256) void k_xcvt2(const float* __restrict__ x,
    const float* __restrict__ lng, const float* __restrict__ lnb,
    ushort_t* __restrict__ xbf, ushort_t* __restrict__ xlnbf, float* __restrict__ outp,
    float* __restrict__ partialA){
    int w = threadIdx.x >> 6, lane = threadIdx.x & 63;
    int row = blockIdx.x*4 + w;
    size_t i4 = (size_t)row*64 + lane;
    f32x4 v = __builtin_nontemporal_load((const f32x4*)x + i4);
    *((f32x4*)outp + i4) = v;
    float vv[4] = {v[0], v[1], v[2], v[3]};
    __shared__ float sda[4][256];
    *(f32x4*)&sda[w][lane*4] = v;
    float s = (vv[0]+vv[1])+(vv[2]+vv[3]);
    float s2 = (vv[0]*vv[0]+vv[1]*vv[1])+(vv[2]*vv[2]+vv[3]*vv[3]);
    for (int off=32; off; off>>=1){ s += __shfl_down(s, off); s2 += __shfl_down(s2, off); }
    float m = __shfl(s, 0) * (1.0f/DDIM);
    float var = __shfl(s2, 0) * (1.0f/DDIM) - m*m;
    float r = rsqrtf(var + 1e-5f);
    int c0 = lane*4;
    #pragma unroll
    for (int u=0;u<4;++u){
        size_t i = i4*4 + u;
        xbf[i] = f2bf(vv[u]);
        xlnbf[i] = f2bf((vv[u]-m)*r*lng[c0+u] + lnb[c0+u]);
    }
    __syncthreads();
    if (w==0){
        f32x4 a = *(const f32x4*)&sda[0][lane*4];
        f32x4 b4 = *(const f32x4*)&sda[1][lane*4];
        f32x4 c4 = *(const f32x4*)&sda[2][lane*4];
        f32x4 d4 = *(const f32x4*)&sda[3][lane*4];
        f32x4 sum = a + b4 + c4 + d4;
        *(f32x4*)&partialA[(size_t)blockIdx.x*256 + lane*4] = sum;
    }
}

// ---------------- mean stage B ----------------
__global__ __launch_bounds__(256) void k_meanB(const float* __restrict__ partialA, float* __restrict__ partialB){
    int seg = blockIdx.x, b = blockIdx.y, t = threadIdx.x;
    const float* p = partialA + ((size_t)(b*1024 + seg*64))*256 + t;
    float s0=0,s1=0,s2=0,s3=0;
    #pragma unroll
    for (int c=0;c<64;c+=4){
        s0 += p[(size_t)c*256];
        s1 += p[(size_t)(c+1)*256];
        s2 += p[(size_t)(c+2)*256];
        s3 += p[(size_t)(c+3)*256];
    }
    partialB[((size_t)b*16 + seg)*256 + t] = (s0+s1)+(s2+s3);
}

// ---------------- gate layer 1 ----------------
__global__ __launch_bounds__(256) void k_gate1(const float* __restrict__ partial, const float* __restrict__ text,
    const float* __restrict__ g1w, const float* __restrict__ g1b, float* __restrict__ hs){
    int d = blockIdx.x, t = threadIdx.x;
    int w = t >> 6, lane = t & 63;
    float xm[BB];
    #pragma unroll
    for (int b=0;b<BB;++b){
        float s = 0.f;
        #pragma unroll
        for (int c=0;c<16;++c) s += partial[((size_t)b*16 + c)*256 + t];
        xm[b] = s * (1.0f/NN);
    }
    const float* wrow = g1w + (size_t)d*(DDIM+TT);
    float w0 = wrow[t], w1 = wrow[256+t], w2 = wrow[512+t], w3 = wrow[768+t];
    float acc[BB];
    #pragma unroll
    for (int b=0;b<BB;++b){
        const float* tx = text + (size_t)b*TT;
        acc[b] = xm[b]*w0 + tx[t]*w1 + tx[256+t]*w2 + tx[512+t]*w3;
    }
    #pragma unroll
    for (int b=0;b<BB;++b)
        for (int off=32; off; off>>=1) acc[b] += __shfl_down(acc[b], off);
    __shared__ float red[BB][4];
    if (lane==0)
        #pragma unroll
        for (int b=0;b<BB;++b) red[b][w] = acc[b];
    __syncthreads();
    if (t < BB){
        float s = red[t][0]+red[t][1]+red[t][2]+red[t][3] + g1b[d];
        hs[t*DDIM + d] = fmaxf(s, 0.0f);
    }
}

// ---------------- gate layer 2 + top-2 softmax ----------------
__global__ __launch_bounds__(64) void k_gate2(const float* __restrict__ hs,
    const float* __restrict__ g2w, const float* __restrict__ g2b,
    float* __restrict__ combine, float* __restrict__ wout){
    __shared__ float lg[BB][4];
    int t = threadIdx.x;
    if (t < 32){
        int b = t>>2, e = t&3;
        float a = g2b[e];
        const float* w2 = g2w + e*DDIM;
        const float* h = hs + b*DDIM;
        for (int o=0;o<DDIM;o+=4)
            a += h[o]*w2[o] + h[o+1]*w2[o+1] + h[o+2]*w2[o+2] + h[o+3]*w2[o+3];
        lg[b][e] = a;
    }
    __syncthreads();
    if (t < BB){
        int b = t;
        int i1=0; float v1=lg[b][0];
        for (int e=1;e<4;++e){ if (lg[b][e] > v1){ v1=lg[b][e]; i1=e; } }
        int i2=0; float v2=-3.0e38f; bool found=false;
        for (int e=0;e<4;++e){ if (e==i1) continue; if (!found || lg[b][e] > v2){ v2=lg[b][e]; i2=e; found=true; } }
        float e2 = expf(v2 - v1);
        float inv = 1.0f/(1.0f + e2);
        float w0 = inv, w1 = e2*inv;
        float cv[4] = {0.f,0.f,0.f,0.f};
        cv[i1] = w0; cv[i2] = w1;
        for (int e=0;e<4;++e) combine[b*4+e] = cv[e];
        wout[b*2+0] = w0; wout[b*2+1] = w1;
    }
}

// ---------------- weight conversion fp32 -> bf16 ----------------
__global__ __launch_bounds__(256) void k_cvtw(
    const float* __restrict__ s0, const float* __restrict__ s1, const float* __restrict__ s2,
    const float* __restrict__ s3, const float* __restrict__ s4, const float* __restrict__ s5,
    const float* __restrict__ s6, const float* __restrict__ s7, const float* __restrict__ s8,
    ushort_t* __restrict__ dst){
    const int off[10] = {0,196608,262144,524288,786432,1048576,1310720,1572864,1835008,1900544};
    const float* srcs[9] = {s0,s1,s2,s3,s4,s5,s6,s7,s8};
    int i = (blockIdx.x*256 + threadIdx.x)*8;
    if (i >= 1900544) return;
    int seg = 0;
    #pragma unroll
    for (int k=1;k<9;++k) if (i >= off[k]) seg = k;
    const float* s = srcs[seg] + (i - off[seg]);
    ushort_t* d = dst + i;
    #pragma unroll
    for (int u=0;u<8;++u) d[u] = f2bf(s[u]);
}

// ---------------- fused: V2 stats + LN2(V2) -> bf16 (gated expert 2) ----------------
__global__ __launch_bounds__(256) void k_v2cvt2(const float* __restrict__ v2,
    const float* __restrict__ lng, const float* __restrict__ lnb,
    ushort_t* __restrict__ dstbf, const float* __restrict__ combine){
    int w = threadIdx.x >> 6, lane = threadIdx.x & 63;
    int row = blockIdx.x*4 + w;
    if (combine[(row>>12)*4+2]==0.0f) return;
    size_t i4 = (size_t)row*64 + lane;
    f32x4 v = *((const f32x4*)v2 + i4);
    float vv[4] = {v[0], v[1], v[2], v[3]};
    float s = (vv[0]+vv[1])+(vv[2]+vv[3]);
    float s2 = (vv[0]*vv[0]+vv[1]*vv[1])+(vv[2]*vv[2]+vv[3]*vv[3]);
    for (int off=32; off; off>>=1){ s += __shfl_down(s, off); s2 += __shfl_down(s2, off); }
    float m = __shfl(s, 0) * (1.0f/DDIM);
    float var = __shfl(s2, 0) * (1.0f/DDIM) - m*m;
    float r = rsqrtf(var + 1e-5f);
    int c0 = lane*4;
    #pragma unroll
    for (int u=0;u<4;++u)
        dstbf[i4*4+u] = f2bf((vv[u]-m)*r*lng[c0+u] + lnb[c0+u]);
}

// ---------------- fused transpose + forward DFT along W (bf16 in, packed bf16 out) ----------------
__global__ __launch_bounds__(256) void k_fft_w2(const ushort_t* __restrict__ xbf, unsigned int* __restrict__ F1pk,
                                                const float* __restrict__ combine){
    int h = blockIdx.x, b = blockIdx.y;
    if (combine[b*4+0]==0.0f) return;
    __shared__ ushort_t img[64*256];   // 32 KB
    __shared__ float ct[64], st[64];
    int t = threadIdx.x;
    if (t < 64){ float ang = (float)t * 0.09817477042468103f; ct[t]=cosf(ang); st[t]=sinf(ang); }
    {
        const uint4* src = (const uint4*)(xbf + ((size_t)b*NN + h*64)*DDIM);
        uint4* dst4 = (uint4*)img;
        for (int i=t; i<2048; i+=256) dst4[i] = src[i];
    }
    __syncthreads();
    float re[16], im[16];
    #pragma unroll
    for (int ky=0;ky<16;++ky){ re[ky]=0.f; im[ky]=0.f; }
    for (int w=0; w<64; ++w){
        float v = bf2f(img[w*256 + t]);
        #pragma unroll
        for (int ky=0; ky<16; ++ky){
            int m = (ky*w)&63;
            re[ky] += v*ct[m];
            im[ky] -= v*st[m];
        }
    }
    unsigned int pk[16];
    #pragma unroll
    for (int ky=0;ky<16;++ky) pk[ky] = pack_cx(re[ky], im[ky]);
    uint4* o = (uint4*)(F1pk + ((size_t)(b*DDIM + t))*1024 + h*16);
    o[0] = *(const uint4*)&pk[0];
    o[1] = *(const uint4*)&pk[4];
    o[2] = *(const uint4*)&pk[8];
    o[3] = *(const uint4*)&pk[12];
}

// ---------------- forward DFT along H (packed bf16 in) -> packed bf16 F2, layout [b][i][c*256+m] ----------------
__global__ __launch_bounds__(256) void k_fft_h(const unsigned int* __restrict__ F1pk,
                                               unsigned int* __restrict__ F2pk,
                                               const float* __restrict__ combine){
    int bd = blockIdx.x; int b = bd>>8;
    if (combine[b*4+0]==0.0f) return;
    __shared__ unsigned int f1[1024];
    __shared__ float ct[64], st[64];
    int t = threadIdx.x;
    if (t < 64){ float ang = (float)t * 0.09817477042468103f; ct[t]=cosf(ang); st[t]=sinf(ang); }
    {
        const uint4* src = (const uint4*)(F1pk + (size_t)bd*1024);
        ((uint4*)f1)[t] = src[t];    // 256 uint4 = 1024 u32
    }
    __syncthreads();
    for (int task=t; task<512; task+=256){
        int c = task>>8, kxp = (task>>4)&15, ky = task&15;
        int kx = c ? 48+kxp : kxp;
        float re=0.f, im=0.f;
        #pragma unroll
        for (int h=0;h<64;++h){
            int m = (kx*h)&63;
            unsigned int p = f1[h*16+ky];
            float ar = pk_re(p), ai = pk_im(p);
            re += ar*ct[m] + ai*st[m];
            im += ai*ct[m] - ar*st[m];
        }
        F2pk[(size_t)bd*512 + task] = pack_cx(re, im);
    }
}

// ---------------- spectral multiply v12: minimal-VGPR + NONTEMPORAL weight stream ----------------
// grid: (128 o-pairs, 2 halves, 8 i-chunks of 32); thread t = mode within half.
__global__ __launch_bounds__(256, 8) void k_specmul12(const unsigned int* __restrict__ F2pk,
    const float* __restrict__ w1r, const float* __restrict__ w1i,
    const float* __restrict__ w2r, const float* __restrict__ w2i,
    float* __restrict__ Gp, const float* __restrict__ combine){
    bool any=false;
    for (int b=0;b<BB;++b) any = any || (combine[b*4]!=0.0f);
    if (!any) return;
    int t  = threadIdx.x;
    int o0 = blockIdx.x * 2;
    int c  = blockIdx.y;
    int s  = blockIdx.z;
    const float* Wr0 = (c ? w2r : w1r) + ((size_t)(s*32)*DDIM + o0)*256 + t;
    const float* Wi0 = (c ? w2i : w1i) + ((size_t)(s*32)*DDIM + o0)*256 + t;
    const unsigned int* Fp = F2pk + (size_t)(s*32)*512 + c*256 + t;
    float ar[2][BB], ai[2][BB];
    #pragma unroll
    for (int oo=0;oo<2;++oo)
        #pragma unroll
        for (int b=0;b<BB;++b){ ar[oo][b]=0.f; ai[oo][b]=0.f; }
    for (int ii=0; ii<32; ++ii){
        float wr0 = __builtin_nontemporal_load(Wr0);
        float wr1 = __builtin_nontemporal_load(Wr0 + 256);
        float wi0 = __builtin_nontemporal_load(Wi0);
        float wi1 = __builtin_nontemporal_load(Wi0 + 256);
        unsigned int f[BB];
        #pragma unroll
        for (int b=0;b<BB;++b)
            f[b] = Fp[(size_t)b*131072];
        Wr0 += 65536; Wi0 += 65536; Fp += 512;
        #pragma unroll
        for (int b=0;b<BB;++b){
            float fr = pk_re(f[b]);
            float fi = pk_im(f[b]);
            ar[0][b] += fr*wr0 - fi*wi0;
            ai[0][b] += fr*wi0 + fi*wr0;
            ar[1][b] += fr*wr1 - fi*wi1;
            ai[1][b] += fr*wi1 + fi*wr1;
        }
    }
    #pragma unroll
    for (int oo=0;oo<2;++oo)
        for (int b=0;b<BB;++b){
            float* g = Gp + ((((size_t)s*BB + b)*DDIM + o0+oo)*512 + c*256 + t)*2;
            __builtin_nontemporal_store(ar[oo][b], g);
            __builtin_nontemporal_store(ai[oo][b], g+1);
        }
}

// ---------------- inverse DFT along H (fused 8-partial reduce, NT Gp reads, packed Z out) ----------------
__global__ __launch_bounds__(256) void k_ifft_h(const float* __restrict__ Gp, unsigned int* __restrict__ Zpk,
                                                const float* __restrict__ combine){
    int bd = blockIdx.x; int b = bd>>8;
    if (combine[b*4+0]==0.0f) return;
    __shared__ float g[1024];
    __shared__ float ct[64], st[64];
    int t=threadIdx.x;
    if (t < 64){ float ang = (float)t * 0.09817477042468103f; ct[t]=cosf(ang); st[t]=sinf(ang); }
    {
        f32x4 v = (f32x4){0.f,0.f,0.f,0.f};
        #pragma unroll
        for (int s=0;s<8;++s){
            const f32x4* p = (const f32x4*)(Gp + (size_t)s*2097152 + (size_t)bd*1024);
            v += __builtin_nontemporal_load(p + t);
        }
        *(f32x4*)(g + t*4) = v;
    }
    __syncthreads();
    for (int task=t;task<1024;task+=256){
        int h=task>>4, ky=task&15;
        float re=0.f, im=0.f;
        #pragma unroll
        for (int c=0;c<2;++c){
            #pragma unroll
            for (int kxp=0;kxp<16;++kxp){
                int kx = c ? 48+kxp : kxp;
                int m = (kx*h)&63;
                int gi = (c*256 + kxp*16 + ky)*2;
                float gr=g[gi], gim=g[gi+1];
                re += gr*ct[m] - gim*st[m];
                im += gr*st[m] + gim*ct[m];
            }
        }
        Zpk[(size_t)bd*1024 + task] = pack_cx(re*(1.0f/64.0f), im*(1.0f/64.0f));
    }
}

// ---------------- FNO output (packed Z in, X2 in bf16) ----------------
__global__ __launch_bounds__(256) void k_fno_out(const unsigned int* __restrict__ Zpk, const ushort_t* __restrict__ X2,
    const float* __restrict__ combine, float* __restrict__ out){
    int h = blockIdx.x, b = blockIdx.y;
    float cb = combine[b*4];
    if (cb==0.0f) return;
    __shared__ float ct[64], st[64];
    int t = threadIdx.x;
    if (t < 64){ float ang = (float)t * 0.09817477042468103f; ct[t]=cosf(ang); st[t]=sinf(ang); }
    __syncthreads();
    float zr[16], zi[16];
    const uint4* zp = (const uint4*)(Zpk + ((size_t)(b*DDIM + t))*1024 + h*16);
    #pragma unroll
    for (int q=0;q<4;++q){
        uint4 z = zp[q];
        const unsigned int zz[4] = {z.x, z.y, z.z, z.w};
        #pragma unroll
        for (int u=0;u<4;++u){
            zr[q*4+u] = pk_re(zz[u]);
            zi[q*4+u] = pk_im(zz[u]);
        }
    }
    for (int w=0;w<64;++w){
        float s = zr[0];
        #pragma unroll
        for (int ky=1;ky<16;++ky){
            int m = (ky*w)&63;
            s += 2.0f*(zr[ky]*ct[m] - zi[ky]*st[m]);
        }
        s *= (1.0f/64.0f);
        size_t idx = ((size_t)b*NN + h*64 + w)*DDIM + t;
        out[idx] += cb * gelu_f(s + bf2f(__builtin_nontemporal_load(X2 + idx)));
    }
}

// ---------------- MFMA bf16 GEMM ----------------
// EPI: 0 = store bf16; 1 = gelu -> bf16; 2 = out += scale*(v+bias);
//      3 = proj: V2 = x + v (fp32), out += scale*v
template<int EPI>
__global__ __launch_bounds__(256) void k_bgemm(
    const ushort_t* __restrict__ A, const ushort_t* __restrict__ W, const float* __restrict__ bias,
    void* __restrict__ dst, const float* __restrict__ combine, int expert, int K, int N,
    const float* __restrict__ xres, float* __restrict__ out)
{
    int tiles_n = N >> 7;
    int tm = blockIdx.x / tiles_n, tn = blockIdx.x - tm*tiles_n;
    int row0 = tm << 7, col0 = tn << 7;
    float scale = combine[(row0>>12)*4 + expert];
    if (scale == 0.0f) return;
    __shared__ __align__(16) ushort_t As[8192];
    __shared__ __align__(16) ushort_t Bs[8192];
    int t = threadIdx.x;
    int w = t >> 6, lane = t & 63;
    int wr = w >> 1, wc = w & 1;
    int lrow = lane >> 3, lk8 = (lane & 7) * 8;
    f32x4 acc[4][4];
    #pragma unroll
    for (int m=0;m<4;++m)
        #pragma unroll
        for (int n=0;n<4;++n) acc[m][n] = (f32x4){0.f,0.f,0.f,0.f};
    int afr = lane & 15, akr = (lane >> 4) * 8;
    for (int k0=0; k0<K; k0+=64){
        #pragma unroll
        for (int it=0; it<4; ++it){
            int c = it*4 + w;
            const ushort_t* ga = A + (size_t)(row0 + c*8 + lrow)*K + k0 + lk8;
            GLOAD16(ga, As + c*512);
            const ushort_t* gb = W + (size_t)(col0 + c*8 + lrow)*K + k0 + lk8;
            GLOAD16(gb, Bs + c*512);
        }
        __syncthreads();
        #pragma unroll
        for (int kk=0; kk<2; ++kk){
            bf16x8 af[4], bfr[4];
            #pragma unroll
            for (int m=0;m<4;++m)
                af[m] = *(const bf16x8*)(As + (wr*64 + m*16 + afr)*64 + kk*32 + akr);
            #pragma unroll
            for (int n=0;n<4;++n)
                bfr[n] = *(const bf16x8*)(Bs + (wc*64 + n*16 + afr)*64 + kk*32 + akr);
            #pragma unroll
            for (int m=0;m<4;++m)
                #pragma unroll
                for (int n=0;n<4;++n)
                    acc[m][n] = __builtin_amdgcn_mfma_f32_16x16x32_bf16(af[m], bfr[n], acc[m][n], 0, 0, 0);
        }
        __syncthreads();
    }
    int rbase = row0 + wr*64 + (lane>>4)*4;
    int cbase = col0 + wc*64 + (lane&15);
    #pragma unroll
    for (int n=0;n<4;++n){
        int col = cbase + n*16;
        float bcol = bias[col];
        #pragma unroll
        for (int m=0;m<4;++m){
            int r0 = rbase + m*16;
            f32x4 a = acc[m][n];
            #pragma unroll
            for (int j=0;j<4;++j){
                int r = r0 + j;
                float v = a[j] + bcol;
                if (EPI==0)      ((ushort_t*)dst)[(size_t)r*N + col] = f2bf(v);
                else if (EPI==1) ((ushort_t*)dst)[(size_t)r*N + col] = f2bf(gelu_f(v));
                else if (EPI==2) out[(size_t)r*DDIM + col] += scale * v;
                else if (EPI==3){
                    ((float*)dst)[(size_t)r*DDIM + col] = xres[(size_t)r*DDIM + col] + v;
                    out[(size_t)r*DDIM + col] += scale * v;
                }
            }
        }
    }
}

// ---------------- window attention core (bf16 in/out, vectorized + 8-wide blocked) ----------------
__global__ __launch_bounds__(256) void k_attn(const ushort_t* __restrict__ QKV, ushort_t* __restrict__ O,
                                              const float* __restrict__ combine){
    int wh = blockIdx.x;
    int w = wh>>2, head = wh&3;
    int b = w>>6;
    if (combine[b*4+2]==0.0f) return;
    int i1 = (w>>3)&7, i2 = w&7;
    __shared__ float A1[64][64];
    __shared__ float kk[64][65];
    __shared__ float S[64][65];
    int t = threadIdx.x;
    for (int idx=t; idx<512; idx+=256){
        int l = idx>>3, dc8 = (idx&7)*8;
        int n = b*NN + (i1*8 + (l>>3))*64 + i2*8 + (l&7);
        const ushort_t* qrow = QKV + (size_t)n*768 + head*64;
        uint4 qv = *(const uint4*)(qrow + dc8);
        uint4 kv = *(const uint4*)(qrow + 256 + dc8);
        const ushort_t* qp = (const ushort_t*)&qv;
        const ushort_t* kp = (const ushort_t*)&kv;
        #pragma unroll
        for (int u=0;u<8;++u){
            A1[l][dc8+u] = bf2f(qp[u]);
            kk[l][dc8+u] = bf2f(kp[u]);
        }
    }
    __syncthreads();
    for (int idx=t; idx<512; idx+=256){
        int i = idx>>3, j0 = (idx&7)*8;
        float s[8] = {0,0,0,0,0,0,0,0};
        for (int dc=0; dc<64; ++dc){
            float a = A1[i][dc];
            #pragma unroll
            for (int u=0;u<8;++u) s[u] += a * kk[j0+u][dc];
        }
        #pragma unroll
        for (int u=0;u<8;++u) S[i][j0+u] = s[u] * 0.125f;
    }
    __syncthreads();
    for (int idx=t; idx<512; idx+=256){
        int l = idx>>3, dc8 = (idx&7)*8;
        int n = b*NN + (i1*8 + (l>>3))*64 + i2*8 + (l&7);
        uint4 vv = *(const uint4*)(QKV + (size_t)n*768 + 512 + head*64 + dc8);
        const ushort_t* vp = (const ushort_t*)&vv;
        #pragma unroll
        for (int u=0;u<8;++u) A1[l][dc8+u] = bf2f(vp[u]);
    }
    __syncthreads();
    if (t < 64){
        float mx = -3.0e38f;
        for (int j=0;j<64;++j) mx = fmaxf(mx, S[t][j]);
        float sum=0.f;
        for (int j=0;j<64;++j){ float e = __expf(S[t][j]-mx); S[t][j]=e; sum+=e; }
        float inv = 1.0f/sum;
        for (int j=0;j<64;++j) S[t][j] *= inv;
    }
    __syncthreads();
    for (int idx=t; idx<512; idx+=256){
        int i = idx>>3, dc0 = (idx&7)*8;
        float s[8] = {0,0,0,0,0,0,0,0};
        for (int j=0;j<64;++j){
            float p = S[i][j];
            #pragma unroll
            for (int u=0;u<8;++u) s[u] += p * A1[j][dc0+u];
        }
        int n = b*NN + (i1*8 + (i>>3))*64 + i2*8 + (i&7);
        uint4 ov;
        ushort_t* op = (ushort_t*)&ov;
        #pragma unroll
        for (int u=0;u<8;++u) op[u] = f2bf(s[u]);
        *(uint4*)(O + (size_t)n*DDIM + head*64 + dc0) = ov;
    }
}

extern "C" void kernel_launch(void* const* d_in, const int* in_sizes, int n_in,
                              void* d_out, int out_size, void* d_ws, size_t ws_size,
                              hipStream_t stream) {
    (void)in_sizes; (void)n_in; (void)out_size; (void)ws_size;
    const float* x      = (const float*)d_in[0];
    const float* text   = (const float*)d_in[1];
    const float* g1_w   = (const float*)d_in[2];
    const float* g1_b   = (const float*)d_in[3];
    const float* g2_w   = (const float*)d_in[4];
    const float* g2_b   = (const float*)d_in[5];
    const float* w1r    = (const float*)d_in[6];
    const float* w1i    = (const float*)d_in[7];
    const float* w2r    = (const float*)d_in[8];
    const float* w2i    = (const float*)d_in[9];
    const float* fno_cw = (const float*)d_in[10];
    const float* fno_cb = (const float*)d_in[11];
    const float* m1_w1  = (const float*)d_in[12];
    const float* m1_b1  = (const float*)d_in[13];
    const float* m1_w2  = (const float*)d_in[14];
    const float* m1_b2  = (const float*)d_in[15];
    const float* a_ln1w = (const float*)d_in[16];
    const float* a_ln1b = (const float*)d_in[17];
    const float* a_qkvw = (const float*)d_in[18];
    const float* a_qkvb = (const float*)d_in[19];
    const float* a_ow   = (const float*)d_in[20];
    const float* a_ob   = (const float*)d_in[21];
    const float* a_ln2w = (const float*)d_in[22];
    const float* a_ln2b = (const float*)d_in[23];
    const float* a_mw1  = (const float*)d_in[24];
    const float* a_mb1  = (const float*)d_in[25];
    const float* a_mw2  = (const float*)d_in[26];
    const float* a_mb2  = (const float*)d_in[27];
    const float* m2_w1  = (const float*)d_in[28];
    const float* m2_b1  = (const float*)d_in[29];
    const float* m2_w2  = (const float*)d_in[30];
    const float* m2_b2  = (const float*)d_in[31];

    float* out  = (float*)d_out;
    float* wout = out + (size_t)BND;

    float* wsf     = (float*)d_ws;
    float* hs      = wsf;                  // 2048
    float* combine = wsf + 2048;           // 32
    ushort_t* wbf  = (ushort_t*)(wsf + 69632);
    float* partialB = wsf + 1019904;       // 32768 floats
    ushort_t* x_bf   = (ushort_t*)(wsf + 1118208);
    ushort_t* xln_bf = (ushort_t*)(wsf + 5312512);
    float* R1 = wsf + 9506816;
    // gating overlay in R1
    float* partialA = R1;                   // 2,097,152 floats
    // FNO overlays
    float* Gp  = R1;                        // 8 x 2,097,152 floats = 64 MB (overlays F1pk, dead after fft_h)
    unsigned int* F1pk = (unsigned int*)(R1 + 8388608);   // 2,097,152 u32 = 8.4 MB
    unsigned int* Zpk  = (unsigned int*)(R1 + 16777216);  // 2,097,152 u32 = 8.4 MB
    ushort_t* X2_bf = (ushort_t*)(R1 + 20971520);
    unsigned int* F2pk = (unsigned int*)(R1 + 29360128);  // 4 MB
    // attention overlays
    ushort_t* QKV_bf  = (ushort_t*)R1;
    ushort_t* O_bf    = (ushort_t*)(R1 + 12582912);
    float*    V2      = R1 + 16777216;
    ushort_t* v2ln_bf = (ushort_t*)(R1 + 25165824);
    // MLP overlay
    ushort_t* H_bf = (ushort_t*)R1;

    // weight slices inside wbf
    ushort_t* qkvw_bf = wbf + 0;
    ushort_t* ow_bf   = wbf + 196608;
    ushort_t* mw1_bf  = wbf + 262144;
    ushort_t* mw2_bf  = wbf + 524288;
    ushort_t* m1w1_bf = wbf + 786432;
    ushort_t* m1w2_bf = wbf + 1048576;
    ushort_t* m2w1_bf = wbf + 1310720;
    ushort_t* m2w2_bf = wbf + 1572864;
    ushort_t* cw_bf   = wbf + 1835008;

    // prep + gating
    k_xcvt2<<<8192, 256, 0, stream>>>(x, a_ln1w, a_ln1b, x_bf, xln_bf, out, partialA);
    k_meanB<<<dim3(16,BB), 256, 0, stream>>>(partialA, partialB);
    k_gate1<<<256, 256, 0, stream>>>(partialB, text, g1_w, g1_b, hs);
    k_gate2<<<1, 64, 0, stream>>>(hs, g2_w, g2_b, combine, wout);
    k_cvtw<<<928, 256, 0, stream>>>(a_qkvw, a_ow, a_mw1, a_mw2, m1_w1, m1_w2, m2_w1, m2_w2, fno_cw, wbf);

    // ---- expert 0: FNO ----
    k_fft_w2<<<dim3(64,BB), 256, 0, stream>>>(x_bf, F1pk, combine);
    k_fft_h<<<2048, 256, 0, stream>>>(F1pk, F2pk, combine);
    k_specmul12<<<dim3(128,2,8), 256, 0, stream>>>(F2pk, w1r, w1i, w2r, w2i, Gp, combine);
    k_ifft_h<<<2048, 256, 0, stream>>>(Gp, Zpk, combine);
    k_bgemm<0><<<512, 256, 0, stream>>>(x_bf, cw_bf, fno_cb, X2_bf, combine, 0, 256, 256, nullptr, nullptr);
    k_fno_out<<<dim3(64,8), 256, 0, stream>>>(Zpk, X2_bf, combine, out);

    // ---- expert 1: MLP ----
    k_bgemm<1><<<2048, 256, 0, stream>>>(x_bf, m1w1_bf, m1_b1, H_bf, combine, 1, 256, 1024, nullptr, nullptr);
    k_bgemm<2><<<512, 256, 0, stream>>>(H_bf, m1w2_bf, m1_b2, nullptr, combine, 1, 1024, 256, nullptr, out);

    // ---- expert 2: window attention ----
    k_bgemm<0><<<1536, 256, 0, stream>>>(xln_bf, qkvw_bf, a_qkvb, QKV_bf, combine, 2, 256, 768, nullptr, nullptr);
    k_attn<<<2048, 256, 0, stream>>>(QKV_bf, O_bf, combine);
    k_bgemm<3><<<512, 256, 0, stream>>>(O_bf, ow_bf, a_ob, V2, combine, 2, 256, 256, x, out);
    k_v2cvt2<<<8192, 256, 0, stream>>>(V2, a_ln2w, a_ln2b, v2ln_bf, combine);
    k_bgemm<1><<<2048, 256, 0, stream>>>(v2ln_bf, mw1_bf, a_mb1, H_bf, combine, 2, 256, 1024, nullptr, nullptr);
    k_bgemm<2><<<512, 256, 0, stream>>>(H_bf, mw2_bf, a_mb2, nullptr, combine, 2, 1024, 256, nullptr, out);

    // ---- expert 3: MLP ----
    k_bgemm<1><<<2048, 256, 0, stream>>>(x_bf, m2w1_bf, m2_b1, H_bf, combine, 3, 256, 1024, nullptr, nullptr);
    k_bgemm<2><<<512, 256, 0, stream>>>(H_bf, m2w2_bf, m2_b2, nullptr, combine, 3, 1024, 256, nullptr, out);
}

// Round 21
// 515.574 us; speedup vs baseline: 1.0638x; 1.0638x over previous
//
#include <hip/hip_runtime.h>
#include <math.h>

#define BB 8
#define NN 4096
#define DDIM 256
#define TT 768
#define BND (BB*NN*DDIM)

typedef unsigned short ushort_t;
typedef short bf16x8 __attribute__((ext_vector_type(8)));
typedef float f32x4 __attribute__((ext_vector_type(4)));

__device__ __forceinline__ float gelu_f(float v){
    float y = 0.7978845608028654f * v * (1.0f + 0.044715f * v * v);
    float ay = fabsf(y);
    float e = __expf(-2.0f * ay);
    float th = 1.0f - 2.0f * e / (1.0f + e);
    th = copysignf(th, y);
    return 0.5f * v * (1.0f + th);
}
__device__ __forceinline__ ushort_t f2bf(float f){
    union { float f; unsigned int u; } v; v.f = f;
    unsigned int u = v.u;
    u += 0x7FFFu + ((u >> 16) & 1u);
    return (ushort_t)(u >> 16);
}
__device__ __forceinline__ float bf2f(ushort_t h){
    union { unsigned int u; float f; } v; v.u = ((unsigned int)h) << 16;
    return v.f;
}
__device__ __forceinline__ float pk_re(unsigned int p){
    union { unsigned int u; float f; } v; v.u = p << 16; return v.f;
}
__device__ __forceinline__ float pk_im(unsigned int p){
    union { unsigned int u; float f; } v; v.u = p & 0xffff0000u; return v.f;
}
#define GLOAD16(gp, lp) __builtin_amdgcn_global_load_lds( \
    (__attribute__((address_space(1))) const void*)(gp),  \
    (__attribute__((address_space(3))) void*)(lp), 16, 0, 0)

// ---------------- fused: LN stats + out=x copy + x_bf + LN1(x)->xln_bf + mean partials ----------------
__global__ __launch_bounds__(256) void k_xcvt2(const float* __restrict__ x,
    const float* __restrict__ lng, const float* __restrict__ lnb,
    ushort_t* __restrict__ xbf, ushort_t* __restrict__ xlnbf, float* __restrict__ outp,
    float* __restrict__ partialA){
    int w = threadIdx.x >> 6, lane = threadIdx.x & 63;
    int row = blockIdx.x*4 + w;
    size_t i4 = (size_t)row*64 + lane;
    f32x4 v = __builtin_nontemporal_load((const f32x4*)x + i4);
    *((f32x4*)outp + i4) = v;
    float vv[4] = {v[0], v[1], v[2], v[3]};
    __shared__ float sda[4][256];
    *(f32x4*)&sda[w][lane*4] = v;
    float s = (vv[0]+vv[1])+(vv[2]+vv[3]);
    float s2 = (vv[0]*vv[0]+vv[1]*vv[1])+(vv[2]*vv[2]+vv[3]*vv[3]);
    for (int off=32; off; off>>=1){ s += __shfl_down(s, off); s2 += __shfl_down(s2, off); }
    float m = __shfl(s, 0) * (1.0f/DDIM);
    float var = __shfl(s2, 0) * (1.0f/DDIM) - m*m;
    float r = rsqrtf(var + 1e-5f);
    int c0 = lane*4;
    #pragma unroll
    for (int u=0;u<4;++u){
        size_t i = i4*4 + u;
        xbf[i] = f2bf(vv[u]);
        xlnbf[i] = f2bf((vv[u]-m)*r*lng[c0+u] + lnb[c0+u]);
    }
    __syncthreads();
    if (w==0){
        f32x4 a = *(const f32x4*)&sda[0][lane*4];
        f32x4 b4 = *(const f32x4*)&sda[1][lane*4];
        f32x4 c4 = *(const f32x4*)&sda[2][lane*4];
        f32x4 d4 = *(const f32x4*)&sda[3][lane*4];
        f32x4 sum = a + b4 + c4 + d4;
        *(f32x4*)&partialA[(size_t)blockIdx.x*256 + lane*4] = sum;
    }
}

// ---------------- mean stage B ----------------
__global__ __launch_bounds__(256) void k_meanB(const float* __restrict__ partialA, float* __restrict__ partialB){
    int seg = blockIdx.x, b = blockIdx.y, t = threadIdx.x;
    const float* p = partialA + ((size_t)(b*1024 + seg*64))*256 + t;
    float s0=0,s1=0,s2=0,s3=0;
    #pragma unroll
    for (int c=0;c<64;c+=4){
        s0 += p[(size_t)c*256];
        s1 += p[(size_t)(c+1)*256];
        s2 += p[(size_t)(c+2)*256];
        s3 += p[(size_t)(c+3)*256];
    }
    partialB[((size_t)b*16 + seg)*256 + t] = (s0+s1)+(s2+s3);
}

// ---------------- gate layer 1 ----------------
__global__ __launch_bounds__(256) void k_gate1(const float* __restrict__ partial, const float* __restrict__ text,
    const float* __restrict__ g1w, const float* __restrict__ g1b, float* __restrict__ hs){
    int d = blockIdx.x, t = threadIdx.x;
    int w = t >> 6, lane = t & 63;
    float xm[BB];
    #pragma unroll
    for (int b=0;b<BB;++b){
        float s = 0.f;
        #pragma unroll
        for (int c=0;c<16;++c) s += partial[((size_t)b*16 + c)*256 + t];
        xm[b] = s * (1.0f/NN);
    }
    const float* wrow = g1w + (size_t)d*(DDIM+TT);
    float w0 = wrow[t], w1 = wrow[256+t], w2 = wrow[512+t], w3 = wrow[768+t];
    float acc[BB];
    #pragma unroll
    for (int b=0;b<BB;++b){
        const float* tx = text + (size_t)b*TT;
        acc[b] = xm[b]*w0 + tx[t]*w1 + tx[256+t]*w2 + tx[512+t]*w3;
    }
    #pragma unroll
    for (int b=0;b<BB;++b)
        for (int off=32; off; off>>=1) acc[b] += __shfl_down(acc[b], off);
    __shared__ float red[BB][4];
    if (lane==0)
        #pragma unroll
        for (int b=0;b<BB;++b) red[b][w] = acc[b];
    __syncthreads();
    if (t < BB){
        float s = red[t][0]+red[t][1]+red[t][2]+red[t][3] + g1b[d];
        hs[t*DDIM + d] = fmaxf(s, 0.0f);
    }
}

// ---------------- gate layer 2 + top-2 softmax ----------------
__global__ __launch_bounds__(64) void k_gate2(const float* __restrict__ hs,
    const float* __restrict__ g2w, const float* __restrict__ g2b,
    float* __restrict__ combine, float* __restrict__ wout){
    __shared__ float lg[BB][4];
    int t = threadIdx.x;
    if (t < 32){
        int b = t>>2, e = t&3;
        float a = g2b[e];
        const float* w2 = g2w + e*DDIM;
        const float* h = hs + b*DDIM;
        for (int o=0;o<DDIM;o+=4)
            a += h[o]*w2[o] + h[o+1]*w2[o+1] + h[o+2]*w2[o+2] + h[o+3]*w2[o+3];
        lg[b][e] = a;
    }
    __syncthreads();
    if (t < BB){
        int b = t;
        int i1=0; float v1=lg[b][0];
        for (int e=1;e<4;++e){ if (lg[b][e] > v1){ v1=lg[b][e]; i1=e; } }
        int i2=0; float v2=-3.0e38f; bool found=false;
        for (int e=0;e<4;++e){ if (e==i1) continue; if (!found || lg[b][e] > v2){ v2=lg[b][e]; i2=e; found=true; } }
        float e2 = expf(v2 - v1);
        float inv = 1.0f/(1.0f + e2);
        float w0 = inv, w1 = e2*inv;
        float cv[4] = {0.f,0.f,0.f,0.f};
        cv[i1] = w0; cv[i2] = w1;
        for (int e=0;e<4;++e) combine[b*4+e] = cv[e];
        wout[b*2+0] = w0; wout[b*2+1] = w1;
    }
}

// ---------------- weight conversion fp32 -> bf16 ----------------
__global__ __launch_bounds__(256) void k_cvtw(
    const float* __restrict__ s0, const float* __restrict__ s1, const float* __restrict__ s2,
    const float* __restrict__ s3, const float* __restrict__ s4, const float* __restrict__ s5,
    const float* __restrict__ s6, const float* __restrict__ s7, const float* __restrict__ s8,
    ushort_t* __restrict__ dst){
    const int off[10] = {0,196608,262144,524288,786432,1048576,1310720,1572864,1835008,1900544};
    const float* srcs[9] = {s0,s1,s2,s3,s4,s5,s6,s7,s8};
    int i = (blockIdx.x*256 + threadIdx.x)*8;
    if (i >= 1900544) return;
    int seg = 0;
    #pragma unroll
    for (int k=1;k<9;++k) if (i >= off[k]) seg = k;
    const float* s = srcs[seg] + (i - off[seg]);
    ushort_t* d = dst + i;
    #pragma unroll
    for (int u=0;u<8;++u) d[u] = f2bf(s[u]);
}

// ---------------- fused: V2 stats + LN2(V2) -> bf16 (gated expert 2) ----------------
__global__ __launch_bounds__(256) void k_v2cvt2(const float* __restrict__ v2,
    const float* __restrict__ lng, const float* __restrict__ lnb,
    ushort_t* __restrict__ dstbf, const float* __restrict__ combine){
    int w = threadIdx.x >> 6, lane = threadIdx.x & 63;
    int row = blockIdx.x*4 + w;
    if (combine[(row>>12)*4+2]==0.0f) return;
    size_t i4 = (size_t)row*64 + lane;
    f32x4 v = *((const f32x4*)v2 + i4);
    float vv[4] = {v[0], v[1], v[2], v[3]};
    float s = (vv[0]+vv[1])+(vv[2]+vv[3]);
    float s2 = (vv[0]*vv[0]+vv[1]*vv[1])+(vv[2]*vv[2]+vv[3]*vv[3]);
    for (int off=32; off; off>>=1){ s += __shfl_down(s, off); s2 += __shfl_down(s2, off); }
    float m = __shfl(s, 0) * (1.0f/DDIM);
    float var = __shfl(s2, 0) * (1.0f/DDIM) - m*m;
    float r = rsqrtf(var + 1e-5f);
    int c0 = lane*4;
    #pragma unroll
    for (int u=0;u<4;++u)
        dstbf[i4*4+u] = f2bf((vv[u]-m)*r*lng[c0+u] + lnb[c0+u]);
}

// ---------------- fused transpose + forward DFT along W (bf16 input) ----------------
__global__ __launch_bounds__(256) void k_fft_w2(const ushort_t* __restrict__ xbf, float* __restrict__ F1,
                                                const float* __restrict__ combine){
    int h = blockIdx.x, b = blockIdx.y;
    if (combine[b*4+0]==0.0f) return;
    __shared__ ushort_t img[64*256];   // 32 KB
    __shared__ float ct[64], st[64];
    int t = threadIdx.x;
    if (t < 64){ float ang = (float)t * 0.09817477042468103f; ct[t]=cosf(ang); st[t]=sinf(ang); }
    {
        const uint4* src = (const uint4*)(xbf + ((size_t)b*NN + h*64)*DDIM);
        uint4* dst4 = (uint4*)img;
        for (int i=t; i<2048; i+=256) dst4[i] = src[i];
    }
    __syncthreads();
    float re[16], im[16];
    #pragma unroll
    for (int ky=0;ky<16;++ky){ re[ky]=0.f; im[ky]=0.f; }
    for (int w=0; w<64; ++w){
        float v = bf2f(img[w*256 + t]);
        #pragma unroll
        for (int ky=0; ky<16; ++ky){
            int m = (ky*w)&63;
            re[ky] += v*ct[m];
            im[ky] -= v*st[m];
        }
    }
    float2* o = (float2*)(F1 + (((size_t)(b*DDIM + t))*1024 + h*16)*2);
    #pragma unroll
    for (int ky=0;ky<16;++ky) o[ky] = make_float2(re[ky], im[ky]);
}

// ---------------- forward DFT along H -> packed bf16, layout [b][i][c*256+m] ----------------
__global__ __launch_bounds__(256) void k_fft_h(const float* __restrict__ F1,
                                               unsigned int* __restrict__ F2pk,
                                               const float* __restrict__ combine){
    int bd = blockIdx.x; int b = bd>>8;
    if (combine[b*4+0]==0.0f) return;
    __shared__ float f1[2048];
    __shared__ float ct[64], st[64];
    int t = threadIdx.x;
    if (t < 64){ float ang = (float)t * 0.09817477042468103f; ct[t]=cosf(ang); st[t]=sinf(ang); }
    const float* src = F1 + (size_t)bd*2048;
    for (int i=t;i<2048;i+=256) f1[i]=src[i];
    __syncthreads();
    for (int task=t; task<512; task+=256){
        int c = task>>8, kxp = (task>>4)&15, ky = task&15;
        int kx = c ? 48+kxp : kxp;
        float re=0.f, im=0.f;
        #pragma unroll
        for (int h=0;h<64;++h){
            int m = (kx*h)&63;
            float ar = f1[(h*16+ky)*2], ai = f1[(h*16+ky)*2+1];
            re += ar*ct[m] + ai*st[m];
            im += ai*ct[m] - ar*st[m];
        }
        F2pk[(size_t)bd*512 + task] = (((unsigned int)f2bf(im)) << 16) | (unsigned int)f2bf(re);
    }
}

// ---------------- spectral multiply v12: minimal-VGPR + NONTEMPORAL weight stream ----------------
// grid: (128 o-pairs, 2 halves, 8 i-chunks of 32); thread t = mode within half.
__global__ __launch_bounds__(256, 8) void k_specmul12(const unsigned int* __restrict__ F2pk,
    const float* __restrict__ w1r, const float* __restrict__ w1i,
    const float* __restrict__ w2r, const float* __restrict__ w2i,
    float* __restrict__ Gp, const float* __restrict__ combine){
    bool any=false;
    for (int b=0;b<BB;++b) any = any || (combine[b*4]!=0.0f);
    if (!any) return;
    int t  = threadIdx.x;
    int o0 = blockIdx.x * 2;
    int c  = blockIdx.y;
    int s  = blockIdx.z;
    const float* Wr0 = (c ? w2r : w1r) + ((size_t)(s*32)*DDIM + o0)*256 + t;
    const float* Wi0 = (c ? w2i : w1i) + ((size_t)(s*32)*DDIM + o0)*256 + t;
    const unsigned int* Fp = F2pk + (size_t)(s*32)*512 + c*256 + t;
    float ar[2][BB], ai[2][BB];
    #pragma unroll
    for (int oo=0;oo<2;++oo)
        #pragma unroll
        for (int b=0;b<BB;++b){ ar[oo][b]=0.f; ai[oo][b]=0.f; }
    for (int ii=0; ii<32; ++ii){
        float wr0 = __builtin_nontemporal_load(Wr0);
        float wr1 = __builtin_nontemporal_load(Wr0 + 256);
        float wi0 = __builtin_nontemporal_load(Wi0);
        float wi1 = __builtin_nontemporal_load(Wi0 + 256);
        unsigned int f[BB];
        #pragma unroll
        for (int b=0;b<BB;++b)
            f[b] = Fp[(size_t)b*131072];
        Wr0 += 65536; Wi0 += 65536; Fp += 512;
        #pragma unroll
        for (int b=0;b<BB;++b){
            float fr = pk_re(f[b]);
            float fi = pk_im(f[b]);
            ar[0][b] += fr*wr0 - fi*wi0;
            ai[0][b] += fr*wi0 + fi*wr0;
            ar[1][b] += fr*wr1 - fi*wi1;
            ai[1][b] += fr*wi1 + fi*wr1;
        }
    }
    #pragma unroll
    for (int oo=0;oo<2;++oo)
        for (int b=0;b<BB;++b){
            float* g = Gp + ((((size_t)s*BB + b)*DDIM + o0+oo)*512 + c*256 + t)*2;
            __builtin_nontemporal_store(ar[oo][b], g);
            __builtin_nontemporal_store(ai[oo][b], g+1);
        }
}

// ---------------- inverse DFT along H (fused 8-partial reduce, NT Gp reads) ----------------
__global__ __launch_bounds__(256) void k_ifft_h(const float* __restrict__ Gp, float* __restrict__ Z,
                                                const float* __restrict__ combine){
    int bd = blockIdx.x; int b = bd>>8;
    if (combine[b*4+0]==0.0f) return;
    __shared__ float g[1024];
    __shared__ float ct[64], st[64];
    int t=threadIdx.x;
    if (t < 64){ float ang = (float)t * 0.09817477042468103f; ct[t]=cosf(ang); st[t]=sinf(ang); }
    {
        f32x4 v = (f32x4){0.f,0.f,0.f,0.f};
        #pragma unroll
        for (int s=0;s<8;++s){
            const f32x4* p = (const f32x4*)(Gp + (size_t)s*2097152 + (size_t)bd*1024);
            v += __builtin_nontemporal_load(p + t);
        }
        *(f32x4*)(g + t*4) = v;
    }
    __syncthreads();
    for (int task=t;task<1024;task+=256){
        int h=task>>4, ky=task&15;
        float re=0.f, im=0.f;
        #pragma unroll
        for (int c=0;c<2;++c){
            #pragma unroll
            for (int kxp=0;kxp<16;++kxp){
                int kx = c ? 48+kxp : kxp;
                int m = (kx*h)&63;
                int gi = (c*256 + kxp*16 + ky)*2;
                float gr=g[gi], gim=g[gi+1];
                re += gr*ct[m] - gim*st[m];
                im += gr*st[m] + gim*ct[m];
            }
        }
        float2* o = (float2*)(Z + ((size_t)bd*1024 + task)*2);
        *o = make_float2(re*(1.0f/64.0f), im*(1.0f/64.0f));
    }
}

// ---------------- FNO output (X2 in bf16, NT streaming reads) ----------------
__global__ __launch_bounds__(256) void k_fno_out(const float* __restrict__ Z, const ushort_t* __restrict__ X2,
    const float* __restrict__ combine, float* __restrict__ out){
    int h = blockIdx.x, b = blockIdx.y;
    float cb = combine[b*4];
    if (cb==0.0f) return;
    __shared__ float ct[64], st[64];
    int t = threadIdx.x;
    if (t < 64){ float ang = (float)t * 0.09817477042468103f; ct[t]=cosf(ang); st[t]=sinf(ang); }
    __syncthreads();
    float zr[16], zi[16];
    const float* zp = Z + (((size_t)(b*DDIM + t)*64 + h)*16)*2;
    #pragma unroll
    for (int ky=0;ky<16;++ky){
        float vx = __builtin_nontemporal_load(zp + ky*2);
        float vy = __builtin_nontemporal_load(zp + ky*2 + 1);
        zr[ky]=vx; zi[ky]=vy;
    }
    for (int w=0;w<64;++w){
        float s = zr[0];
        #pragma unroll
        for (int ky=1;ky<16;++ky){
            int m = (ky*w)&63;
            s += 2.0f*(zr[ky]*ct[m] - zi[ky]*st[m]);
        }
        s *= (1.0f/64.0f);
        size_t idx = ((size_t)b*NN + h*64 + w)*DDIM + t;
        out[idx] += cb * gelu_f(s + bf2f(__builtin_nontemporal_load(X2 + idx)));
    }
}

// ---------------- MFMA bf16 GEMM ----------------
// EPI: 0 = store bf16; 1 = gelu -> bf16; 2 = out += scale*(v+bias);
//      3 = proj: V2 = x + v (fp32), out += scale*v
template<int EPI>
__global__ __launch_bounds__(256) void k_bgemm(
    const ushort_t* __restrict__ A, const ushort_t* __restrict__ W, const float* __restrict__ bias,
    void* __restrict__ dst, const float* __restrict__ combine, int expert, int K, int N,
    const float* __restrict__ xres, float* __restrict__ out)
{
    int tiles_n = N >> 7;
    int tm = blockIdx.x / tiles_n, tn = blockIdx.x - tm*tiles_n;
    int row0 = tm << 7, col0 = tn << 7;
    float scale = combine[(row0>>12)*4 + expert];
    if (scale == 0.0f) return;
    __shared__ __align__(16) ushort_t As[8192];
    __shared__ __align__(16) ushort_t Bs[8192];
    int t = threadIdx.x;
    int w = t >> 6, lane = t & 63;
    int wr = w >> 1, wc = w & 1;
    int lrow = lane >> 3, lk8 = (lane & 7) * 8;
    f32x4 acc[4][4];
    #pragma unroll
    for (int m=0;m<4;++m)
        #pragma unroll
        for (int n=0;n<4;++n) acc[m][n] = (f32x4){0.f,0.f,0.f,0.f};
    int afr = lane & 15, akr = (lane >> 4) * 8;
    for (int k0=0; k0<K; k0+=64){
        #pragma unroll
        for (int it=0; it<4; ++it){
            int c = it*4 + w;
            const ushort_t* ga = A + (size_t)(row0 + c*8 + lrow)*K + k0 + lk8;
            GLOAD16(ga, As + c*512);
            const ushort_t* gb = W + (size_t)(col0 + c*8 + lrow)*K + k0 + lk8;
            GLOAD16(gb, Bs + c*512);
        }
        __syncthreads();
        #pragma unroll
        for (int kk=0; kk<2; ++kk){
            bf16x8 af[4], bfr[4];
            #pragma unroll
            for (int m=0;m<4;++m)
                af[m] = *(const bf16x8*)(As + (wr*64 + m*16 + afr)*64 + kk*32 + akr);
            #pragma unroll
            for (int n=0;n<4;++n)
                bfr[n] = *(const bf16x8*)(Bs + (wc*64 + n*16 + afr)*64 + kk*32 + akr);
            #pragma unroll
            for (int m=0;m<4;++m)
                #pragma unroll
                for (int n=0;n<4;++n)
                    acc[m][n] = __builtin_amdgcn_mfma_f32_16x16x32_bf16(af[m], bfr[n], acc[m][n], 0, 0, 0);
        }
        __syncthreads();
    }
    int rbase = row0 + wr*64 + (lane>>4)*4;
    int cbase = col0 + wc*64 + (lane&15);
    #pragma unroll
    for (int n=0;n<4;++n){
        int col = cbase + n*16;
        float bcol = bias[col];
        #pragma unroll
        for (int m=0;m<4;++m){
            int r0 = rbase + m*16;
            f32x4 a = acc[m][n];
            #pragma unroll
            for (int j=0;j<4;++j){
                int r = r0 + j;
                float v = a[j] + bcol;
                if (EPI==0)      ((ushort_t*)dst)[(size_t)r*N + col] = f2bf(v);
                else if (EPI==1) ((ushort_t*)dst)[(size_t)r*N + col] = f2bf(gelu_f(v));
                else if (EPI==2) out[(size_t)r*DDIM + col] += scale * v;
                else if (EPI==3){
                    ((float*)dst)[(size_t)r*DDIM + col] = xres[(size_t)r*DDIM + col] + v;
                    out[(size_t)r*DDIM + col] += scale * v;
                }
            }
        }
    }
}

// ---------------- window attention core (bf16 in/out, vectorized + 8-wide blocked) ----------------
__global__ __launch_bounds__(256) void k_attn(const ushort_t* __restrict__ QKV, ushort_t* __restrict__ O,
                                              const float* __restrict__ combine){
    int wh = blockIdx.x;
    int w = wh>>2, head = wh&3;
    int b = w>>6;
    if (combine[b*4+2]==0.0f) return;
    int i1 = (w>>3)&7, i2 = w&7;
    __shared__ float A1[64][64];
    __shared__ float kk[64][65];
    __shared__ float S[64][65];
    int t = threadIdx.x;
    for (int idx=t; idx<512; idx+=256){
        int l = idx>>3, dc8 = (idx&7)*8;
        int n = b*NN + (i1*8 + (l>>3))*64 + i2*8 + (l&7);
        const ushort_t* qrow = QKV + (size_t)n*768 + head*64;
        uint4 qv = *(const uint4*)(qrow + dc8);
        uint4 kv = *(const uint4*)(qrow + 256 + dc8);
        const ushort_t* qp = (const ushort_t*)&qv;
        const ushort_t* kp = (const ushort_t*)&kv;
        #pragma unroll
        for (int u=0;u<8;++u){
            A1[l][dc8+u] = bf2f(qp[u]);
            kk[l][dc8+u] = bf2f(kp[u]);
        }
    }
    __syncthreads();
    for (int idx=t; idx<512; idx+=256){
        int i = idx>>3, j0 = (idx&7)*8;
        float s[8] = {0,0,0,0,0,0,0,0};
        for (int dc=0; dc<64; ++dc){
            float a = A1[i][dc];
            #pragma unroll
            for (int u=0;u<8;++u) s[u] += a * kk[j0+u][dc];
        }
        #pragma unroll
        for (int u=0;u<8;++u) S[i][j0+u] = s[u] * 0.125f;
    }
    __syncthreads();
    for (int idx=t; idx<512; idx+=256){
        int l = idx>>3, dc8 = (idx&7)*8;
        int n = b*NN + (i1*8 + (l>>3))*64 + i2*8 + (l&7);
        uint4 vv = *(const uint4*)(QKV + (size_t)n*768 + 512 + head*64 + dc8);
        const ushort_t* vp = (const ushort_t*)&vv;
        #pragma unroll
        for (int u=0;u<8;++u) A1[l][dc8+u] = bf2f(vp[u]);
    }
    __syncthreads();
    if (t < 64){
        float mx = -3.0e38f;
        for (int j=0;j<64;++j) mx = fmaxf(mx, S[t][j]);
        float sum=0.f;
        for (int j=0;j<64;++j){ float e = __expf(S[t][j]-mx); S[t][j]=e; sum+=e; }
        float inv = 1.0f/sum;
        for (int j=0;j<64;++j) S[t][j] *= inv;
    }
    __syncthreads();
    for (int idx=t; idx<512; idx+=256){
        int i = idx>>3, dc0 = (idx&7)*8;
        float s[8] = {0,0,0,0,0,0,0,0};
        for (int j=0;j<64;++j){
            float p = S[i][j];
            #pragma unroll
            for (int u=0;u<8;++u) s[u] += p * A1[j][dc0+u];
        }
        int n = b*NN + (i1*8 + (i>>3))*64 + i2*8 + (i&7);
        uint4 ov;
        ushort_t* op = (ushort_t*)&ov;
        #pragma unroll
        for (int u=0;u<8;++u) op[u] = f2bf(s[u]);
        *(uint4*)(O + (size_t)n*DDIM + head*64 + dc0) = ov;
    }
}

extern "C" void kernel_launch(void* const* d_in, const int* in_sizes, int n_in,
                              void* d_out, int out_size, void* d_ws, size_t ws_size,
                              hipStream_t stream) {
    (void)in_sizes; (void)n_in; (void)out_size; (void)ws_size;
    const float* x      = (const float*)d_in[0];
    const float* text   = (const float*)d_in[1];
    const float* g1_w   = (const float*)d_in[2];
    const float* g1_b   = (const float*)d_in[3];
    const float* g2_w   = (const float*)d_in[4];
    const float* g2_b   = (const float*)d_in[5];
    const float* w1r    = (const float*)d_in[6];
    const float* w1i    = (const float*)d_in[7];
    const float* w2r    = (const float*)d_in[8];
    const float* w2i    = (const float*)d_in[9];
    const float* fno_cw = (const float*)d_in[10];
    const float* fno_cb = (const float*)d_in[11];
    const float* m1_w1  = (const float*)d_in[12];
    const float* m1_b1  = (const float*)d_in[13];
    const float* m1_w2  = (const float*)d_in[14];
    const float* m1_b2  = (const float*)d_in[15];
    const float* a_ln1w = (const float*)d_in[16];
    const float* a_ln1b = (const float*)d_in[17];
    const float* a_qkvw = (const float*)d_in[18];
    const float* a_qkvb = (const float*)d_in[19];
    const float* a_ow   = (const float*)d_in[20];
    const float* a_ob   = (const float*)d_in[21];
    const float* a_ln2w = (const float*)d_in[22];
    const float* a_ln2b = (const float*)d_in[23];
    const float* a_mw1  = (const float*)d_in[24];
    const float* a_mb1  = (const float*)d_in[25];
    const float* a_mw2  = (const float*)d_in[26];
    const float* a_mb2  = (const float*)d_in[27];
    const float* m2_w1  = (const float*)d_in[28];
    const float* m2_b1  = (const float*)d_in[29];
    const float* m2_w2  = (const float*)d_in[30];
    const float* m2_b2  = (const float*)d_in[31];

    float* out  = (float*)d_out;
    float* wout = out + (size_t)BND;

    float* wsf     = (float*)d_ws;
    float* hs      = wsf;                  // 2048
    float* combine = wsf + 2048;           // 32
    ushort_t* wbf  = (ushort_t*)(wsf + 69632);
    float* partialB = wsf + 1019904;       // 32768 floats
    ushort_t* x_bf   = (ushort_t*)(wsf + 1118208);
    ushort_t* xln_bf = (ushort_t*)(wsf + 5312512);
    float* R1 = wsf + 9506816;
    // gating overlay in R1
    float* partialA = R1;                   // 2,097,152 floats
    // FNO overlays
    float* Gp  = R1;                        // 8 x 2,097,152 floats = 64 MB (overlays F1, dead after fft_h)
    float* F1  = R1 + 8388608;
    float* Z   = R1 + 16777216;
    ushort_t* X2_bf = (ushort_t*)(R1 + 20971520);
    unsigned int* F2pk = (unsigned int*)(R1 + 29360128);  // 4 MB
    // attention overlays
    ushort_t* QKV_bf  = (ushort_t*)R1;
    ushort_t* O_bf    = (ushort_t*)(R1 + 12582912);
    float*    V2      = R1 + 16777216;
    ushort_t* v2ln_bf = (ushort_t*)(R1 + 25165824);
    // MLP overlay
    ushort_t* H_bf = (ushort_t*)R1;

    // weight slices inside wbf
    ushort_t* qkvw_bf = wbf + 0;
    ushort_t* ow_bf   = wbf + 196608;
    ushort_t* mw1_bf  = wbf + 262144;
    ushort_t* mw2_bf  = wbf + 524288;
    ushort_t* m1w1_bf = wbf + 786432;
    ushort_t* m1w2_bf = wbf + 1048576;
    ushort_t* m2w1_bf = wbf + 1310720;
    ushort_t* m2w2_bf = wbf + 1572864;
    ushort_t* cw_bf   = wbf + 1835008;

    // prep + gating
    k_xcvt2<<<8192, 256, 0, stream>>>(x, a_ln1w, a_ln1b, x_bf, xln_bf, out, partialA);
    k_meanB<<<dim3(16,BB), 256, 0, stream>>>(partialA, partialB);
    k_gate1<<<256, 256, 0, stream>>>(partialB, text, g1_w, g1_b, hs);
    k_gate2<<<1, 64, 0, stream>>>(hs, g2_w, g2_b, combine, wout);
    k_cvtw<<<928, 256, 0, stream>>>(a_qkvw, a_ow, a_mw1, a_mw2, m1_w1, m1_w2, m2_w1, m2_w2, fno_cw, wbf);

    // ---- expert 0: FNO ----
    k_fft_w2<<<dim3(64,BB), 256, 0, stream>>>(x_bf, F1, combine);
    k_fft_h<<<2048, 256, 0, stream>>>(F1, F2pk, combine);
    k_specmul12<<<dim3(128,2,8), 256, 0, stream>>>(F2pk, w1r, w1i, w2r, w2i, Gp, combine);
    k_ifft_h<<<2048, 256, 0, stream>>>(Gp, Z, combine);
    k_bgemm<0><<<512, 256, 0, stream>>>(x_bf, cw_bf, fno_cb, X2_bf, combine, 0, 256, 256, nullptr, nullptr);
    k_fno_out<<<dim3(64,8), 256, 0, stream>>>(Z, X2_bf, combine, out);

    // ---- expert 1: MLP ----
    k_bgemm<1><<<2048, 256, 0, stream>>>(x_bf, m1w1_bf, m1_b1, H_bf, combine, 1, 256, 1024, nullptr, nullptr);
    k_bgemm<2><<<512, 256, 0, stream>>>(H_bf, m1w2_bf, m1_b2, nullptr, combine, 1, 1024, 256, nullptr, out);

    // ---- expert 2: window attention ----
    k_bgemm<0><<<1536, 256, 0, stream>>>(xln_bf, qkvw_bf, a_qkvb, QKV_bf, combine, 2, 256, 768, nullptr, nullptr);
    k_attn<<<2048, 256, 0, stream>>>(QKV_bf, O_bf, combine);
    k_bgemm<3><<<512, 256, 0, stream>>>(O_bf, ow_bf, a_ob, V2, combine, 2, 256, 256, x, out);
    k_v2cvt2<<<8192, 256, 0, stream>>>(V2, a_ln2w, a_ln2b, v2ln_bf, combine);
    k_bgemm<1><<<2048, 256, 0, stream>>>(v2ln_bf, mw1_bf, a_mb1, H_bf, combine, 2, 256, 1024, nullptr, nullptr);
    k_bgemm<2><<<512, 256, 0, stream>>>(H_bf, mw2_bf, a_mb2, nullptr, combine, 2, 1024, 256, nullptr, out);

    // ---- expert 3: MLP ----
    k_bgemm<1><<<2048, 256, 0, stream>>>(x_bf, m2w1_bf, m2_b1, H_bf, combine, 3, 256, 1024, nullptr, nullptr);
    k_bgemm<2><<<512, 256, 0, stream>>>(H_bf, m2w2_bf, m2_b2, nullptr, combine, 3, 1024, 256, nullptr, out);
}